// Round 1
// baseline (83.565 us; speedup 1.0000x reference)
//
#include <hip/hip_runtime.h>

// DAG reachability closure from node 0. N=8192 nodes, left/right child in
// [-1, N). Reference = N relaxation steps == transitive closure from node 0.
//
// Frontier-queue BFS in LDS, single workgroup of 256 threads (4 waves):
//   - edges packed int2 (left,right) in LDS -> one ds_read_b64 per expansion
//   - visited = 1 KB bitmask; atomicOr old-value gives exclusive ownership,
//     so each reachable node is enqueued and expanded EXACTLY once (O(E) work)
//   - append-only queue Q (<= N entries, no resets); per-level [head,end)
//     window, balanced across threads -> no worst-thread serialization
//   - pushes are wave-aggregated: one ballot + one leader atomicAdd per push
//     point, so the tail counter sees ~2 atomics/wave/level, not per-push
//   - 4-wave barriers (vs 16-wave before): ~4x cheaper level sync
// Output: bool mask -> INT32 0/1 (harness reads bool output as int32).

#define NMAX 8192
#define BLK  256

__global__ __launch_bounds__(BLK) void dag_reach_kernel(
    const int* __restrict__ left,
    const int* __restrict__ right,
    int* __restrict__ out,
    int n)
{
    __shared__ int2 sLR[NMAX];               // 64 KB: packed (left, right)
    __shared__ int  Q[NMAX];                 // 32 KB: append-only BFS queue
    __shared__ unsigned int vis[NMAX / 32];  // 1 KB: reachable bitmask
    __shared__ int s_tail;                   // queue tail (atomic append)
    __shared__ int s_end;                    // per-level snapshot of tail

    const int tid  = threadIdx.x;
    const int lane = tid & 63;

    // Stage edges: vectorized int4 global loads, interleaved int2 LDS writes.
    for (int i = 4 * tid; i < n; i += 4 * BLK) {
        int4 l4 = *reinterpret_cast<const int4*>(left  + i);
        int4 r4 = *reinterpret_cast<const int4*>(right + i);
        sLR[i + 0] = make_int2(l4.x, r4.x);
        sLR[i + 1] = make_int2(l4.y, r4.y);
        sLR[i + 2] = make_int2(l4.z, r4.z);
        sLR[i + 3] = make_int2(l4.w, r4.w);
    }
    for (int i = tid; i < NMAX / 32; i += BLK) vis[i] = 0u;
    __syncthreads();

    if (tid == 0) {
        vis[0] = 1u;   // node 0 always reachable
        Q[0]   = 0;
        s_tail = 1;
    }

    int head = 0;
    while (true) {
        if (tid == 0) s_end = s_tail;   // snapshot after prev level's pushes
        __syncthreads();                // (1) snapshot + prior pushes visible
        const int end = s_end;
        if (head == end) break;         // uniform: queue drained -> fixpoint

        for (int i = head + tid; i < end; i += BLK) {
            const int  v  = Q[i];
            const int2 lr = sLR[v];

            // ---- left child ----
            const int cl = lr.x;
            bool pushL = false;
            if (cl >= 0) {
                const unsigned bit = 1u << (cl & 31);
                const unsigned old = atomicOr(&vis[cl >> 5], bit);
                pushL = (old & bit) == 0u;   // we won ownership of cl
            }
            unsigned long long bL = __ballot(pushL);
            if (bL) {
                const int leader = __ffsll(bL) - 1;
                int base = 0;
                if (lane == leader) base = atomicAdd(&s_tail, __popcll(bL));
                base = __shfl(base, leader);
                if (pushL) {
                    const int idx = base + __popcll(bL & ((1ull << lane) - 1ull));
                    Q[idx] = cl;
                }
            }

            // ---- right child ----
            const int cr = lr.y;
            bool pushR = false;
            if (cr >= 0) {
                const unsigned bit = 1u << (cr & 31);
                const unsigned old = atomicOr(&vis[cr >> 5], bit);
                pushR = (old & bit) == 0u;
            }
            unsigned long long bR = __ballot(pushR);
            if (bR) {
                const int leader = __ffsll(bR) - 1;
                int base = 0;
                if (lane == leader) base = atomicAdd(&s_tail, __popcll(bR));
                base = __shfl(base, leader);
                if (pushR) {
                    const int idx = base + __popcll(bR & ((1ull << lane) - 1ull));
                    Q[idx] = cr;
                }
            }
        }
        head = end;
        __syncthreads();                // (2) this level's pushes done
    }

    // Write bool mask as int32 0/1, vectorized (16 B per lane, coalesced).
    for (int i = 4 * tid; i < n; i += 4 * BLK) {
        const unsigned w = vis[i >> 5];
        const int b = i & 31;
        *reinterpret_cast<int4*>(out + i) =
            make_int4((int)((w >> (b + 0)) & 1u),
                      (int)((w >> (b + 1)) & 1u),
                      (int)((w >> (b + 2)) & 1u),
                      (int)((w >> (b + 3)) & 1u));
    }
}

extern "C" void kernel_launch(void* const* d_in, const int* in_sizes, int n_in,
                              void* d_out, int out_size, void* d_ws, size_t ws_size,
                              hipStream_t stream)
{
    // inputs: 0 = thresholds (f32, UNUSED by reference), 1 = left (i32), 2 = right (i32)
    const int* left  = (const int*)d_in[1];
    const int* right = (const int*)d_in[2];
    int* out = (int*)d_out;
    const int n = in_sizes[1];

    dag_reach_kernel<<<1, BLK, 0, stream>>>(left, right, out, n);
}

// Round 2
// 74.891 us; speedup vs baseline: 1.1158x; 1.1158x over previous
//
#include <hip/hip_runtime.h>

// DAG reachability closure from node 0. N=8192 nodes, left/right child in
// [-1, N). Reference = N relaxation steps == transitive closure from node 0.
//
// Chaotic bitmask relaxation in LDS (the round-0 winner's core), restructured:
//   - 256 threads = 4 waves (vs 16): ~4x cheaper __syncthreads
//   - thread t owns reach word t (nodes 32t..32t+31), private 'expanded' mask
//     makes total expansion work O(E) (each node's edges pushed exactly once)
//   - INNER=4 barrier-free sub-iterations per pass: LDS atomics are visible
//     immediately, so each barrier-synced pass propagates >=4 BFS hops ->
//     pass count ~ depth/4, cutting the dominant per-pass sync cost
//   - edges packed int2 in LDS: one ds_read_b64 per expanded node
//   - expansion pipelined 4 nodes wide: 4 independent ds_read_b64 in flight
//     per lgkmcnt wait (bounds worst-thread serial latency at peak levels)
//   - atomicOr is fire-and-forget (result never consumed -> off critical path)
// Output: bool mask -> INT32 0/1 (harness reads bool output as int32).

#define NMAX   8192
#define BLK    256
#define NWORDS (NMAX / 32)   // 256 == BLK: one reach word per thread
#define INNER  4

__global__ __launch_bounds__(BLK) void dag_reach_kernel(
    const int* __restrict__ left,
    const int* __restrict__ right,
    int* __restrict__ out,
    int n)
{
    __shared__ int2 sLR[NMAX];               // 64 KB: packed (left, right)
    __shared__ unsigned int reach[NWORDS];   // 1 KB: reachable bitmask
    __shared__ int s_changed;

    const int tid = threadIdx.x;

    // Stage edges: vectorized int4 global loads, packed int2 LDS writes.
    for (int i = 4 * tid; i < n; i += 4 * BLK) {
        int4 l4 = *reinterpret_cast<const int4*>(left  + i);
        int4 r4 = *reinterpret_cast<const int4*>(right + i);
        sLR[i + 0] = make_int2(l4.x, r4.x);
        sLR[i + 1] = make_int2(l4.y, r4.y);
        sLR[i + 2] = make_int2(l4.z, r4.z);
        sLR[i + 3] = make_int2(l4.w, r4.w);
    }
    reach[tid] = (tid == 0) ? 1u : 0u;       // node 0 always reachable
    __syncthreads();

    unsigned int expanded = 0u;              // bits of my word already pushed
    const int base = tid * 32;
    volatile unsigned int* vreach = reach;   // force re-read each sub-iter

    while (true) {
        if (tid == 0) s_changed = 0;
        __syncthreads();

        int localChanged = 0;
        #pragma unroll
        for (int it = 0; it < INNER; ++it) {
            unsigned int pend = vreach[tid] & ~expanded;
            if (pend) {
                localChanged = 1;
                expanded |= pend;
                while (pend) {
                    // peel up to 4 pending bits -> 4 independent edge reads
                    int b0 = __ffs(pend) - 1; pend &= pend - 1;
                    int b1 = -1, b2 = -1, b3 = -1;
                    if (pend) { b1 = __ffs(pend) - 1; pend &= pend - 1;
                        if (pend) { b2 = __ffs(pend) - 1; pend &= pend - 1;
                            if (pend) { b3 = __ffs(pend) - 1; pend &= pend - 1; } } }
                    int2 lr0 = sLR[base + b0];
                    int2 lr1 = sLR[base + (b1 < 0 ? b0 : b1)];
                    int2 lr2 = sLR[base + (b2 < 0 ? b0 : b2)];
                    int2 lr3 = sLR[base + (b3 < 0 ? b0 : b3)];
                    if (lr0.x >= 0) atomicOr(&reach[lr0.x >> 5], 1u << (lr0.x & 31));
                    if (lr0.y >= 0) atomicOr(&reach[lr0.y >> 5], 1u << (lr0.y & 31));
                    if (b1 >= 0) {
                        if (lr1.x >= 0) atomicOr(&reach[lr1.x >> 5], 1u << (lr1.x & 31));
                        if (lr1.y >= 0) atomicOr(&reach[lr1.y >> 5], 1u << (lr1.y & 31));
                    }
                    if (b2 >= 0) {
                        if (lr2.x >= 0) atomicOr(&reach[lr2.x >> 5], 1u << (lr2.x & 31));
                        if (lr2.y >= 0) atomicOr(&reach[lr2.y >> 5], 1u << (lr2.y & 31));
                    }
                    if (b3 >= 0) {
                        if (lr3.x >= 0) atomicOr(&reach[lr3.x >> 5], 1u << (lr3.x & 31));
                        if (lr3.y >= 0) atomicOr(&reach[lr3.y >> 5], 1u << (lr3.y & 31));
                    }
                }
            }
        }
        if (localChanged) s_changed = 1;     // benign same-value race
        __syncthreads();
        if (!s_changed) break;               // no pend anywhere -> fixpoint
    }

    // Write bool mask as int32 0/1, vectorized (16 B per lane, coalesced).
    for (int i = 4 * tid; i < n; i += 4 * BLK) {
        const unsigned w = reach[i >> 5];
        const int b = i & 31;
        *reinterpret_cast<int4*>(out + i) =
            make_int4((int)((w >> (b + 0)) & 1u),
                      (int)((w >> (b + 1)) & 1u),
                      (int)((w >> (b + 2)) & 1u),
                      (int)((w >> (b + 3)) & 1u));
    }
}

extern "C" void kernel_launch(void* const* d_in, const int* in_sizes, int n_in,
                              void* d_out, int out_size, void* d_ws, size_t ws_size,
                              hipStream_t stream)
{
    // inputs: 0 = thresholds (f32, UNUSED by reference), 1 = left (i32), 2 = right (i32)
    const int* left  = (const int*)d_in[1];
    const int* right = (const int*)d_in[2];
    int* out = (int*)d_out;
    const int n = in_sizes[1];

    dag_reach_kernel<<<1, BLK, 0, stream>>>(left, right, out, n);
}